// Round 6
// baseline (294.909 us; speedup 1.0000x reference)
//
#include <hip/hip_runtime.h>
#include <hip/hip_bf16.h>
#include <stdint.h>

typedef unsigned short u16;
typedef unsigned int   u32;
typedef __attribute__((ext_vector_type(8))) short bf16x8;
typedef __attribute__((ext_vector_type(8))) unsigned short u16x8;
typedef __attribute__((ext_vector_type(4))) float f32x4;
typedef __attribute__((ext_vector_type(4))) _Float16 f16x4;

#define SCALE 0.08838834764831845f
// SCALE * log2(e): scores land directly in exp2 domain (folded into Q)
#define SC2 0.1275174475f

#if __has_builtin(__builtin_amdgcn_mfma_f32_16x16x16_f16)
#define MFMA16(A, B, C) __builtin_amdgcn_mfma_f32_16x16x16_f16(A, B, C, 0, 0, 0)
#else
#define MFMA16(A, B, C) __builtin_amdgcn_mfma_f32_16x16x16f16(A, B, C, 0, 0, 0)
#endif
#define MFMA32(A, B, C) __builtin_amdgcn_mfma_f32_16x16x32_bf16(A, B, C, 0, 0, 0)

__device__ __forceinline__ float bf2f(u16 u) {
    union { u32 i; float f; } t; t.i = ((u32)u) << 16; return t.f;
}
__device__ __forceinline__ u16 f2bf(float f) {
    union { u32 i; float f; } t; t.f = f;
    u32 b = t.i;
    return (u16)((b + 0x7fffu + ((b >> 16) & 1u)) >> 16);
}
__device__ __forceinline__ u16 f2h(float f) {
    union { _Float16 h; u16 u; } c; c.h = (_Float16)f; return c.u;
}

// async global->LDS, 16B per lane, linear LDS dest (wave-uniform base + lane*16)
__device__ __forceinline__ void gload16(const u16* g, u16* l) {
    __builtin_amdgcn_global_load_lds(
        (const __attribute__((address_space(1))) void*)g,
        (__attribute__((address_space(3))) void*)l, 16, 0, 0);
}

// ============================================================
// Kernel 0: GroupNorm stats -> per-channel affine tables.
// ============================================================
__global__ __launch_bounds__(256) void stats_kernel(
    const float* __restrict__ x, const float* __restrict__ gw,
    const float* __restrict__ gb, float* __restrict__ gp, float* __restrict__ bp)
{
    int b = blockIdx.x & 7, g = blockIdx.x >> 3;
    long base = ((long)(b * 128 + g * 4)) << 12;
    const float4* x4 = (const float4*)(x + base);

    float s = 0.f, ss = 0.f;
    for (int i = threadIdx.x; i < 4096; i += 256) {
        float4 v = x4[i];
        s  += v.x + v.y + v.z + v.w;
        ss += v.x * v.x + v.y * v.y + v.z * v.z + v.w * v.w;
    }
    #pragma unroll
    for (int off = 32; off > 0; off >>= 1) {
        s  += __shfl_xor(s,  off);
        ss += __shfl_xor(ss, off);
    }
    __shared__ float red[8];
    int wid = threadIdx.x >> 6;
    if ((threadIdx.x & 63) == 0) { red[wid * 2] = s; red[wid * 2 + 1] = ss; }
    __syncthreads();
    s  = red[0] + red[2] + red[4] + red[6];
    ss = red[1] + red[3] + red[5] + red[7];

    float mean = s * (1.f / 16384.f);
    float var  = ss * (1.f / 16384.f) - mean * mean;
    float rs   = rsqrtf(var + 1e-5f);

    if (threadIdx.x < 4) {
        int c = g * 4 + threadIdx.x;
        float gamma = gw[c] * rs;
        gp[b * 128 + c] = gamma;
        bp[b * 128 + c] = gb[c] - mean * gamma;
    }
}

// ============================================================
// Kernel 0b: w fp32 -> bf16
// ============================================================
__global__ __launch_bounds__(256) void wconv_kernel(
    const float* __restrict__ w, u16* __restrict__ wbf)
{
    int idx = (blockIdx.x * 256 + threadIdx.x) * 4;
    float4 v = *(const float4*)&w[idx];
    ushort4 o = { f2bf(v.x), f2bf(v.y), f2bf(v.z), f2bf(v.w) };
    *(ushort4*)&wbf[idx] = o;
}

// ============================================================
// Kernel 1: apply GN + transpose -> hn [b][s][c] bf16.
// ============================================================
__global__ __launch_bounds__(256) void apply_kernel(
    const float* __restrict__ x, const float* __restrict__ gp,
    const float* __restrict__ bp, u16* __restrict__ hn)
{
    __shared__ u16 ldsT[128 * 128];   // 32 KB
    __shared__ float gpl[128], bpl[128];
    int b = blockIdx.x & 7, st = blockIdx.x >> 3;
    int s0 = st << 7;
    int t = threadIdx.x;
    if (t < 128) { gpl[t] = gp[b * 128 + t]; bpl[t] = bp[b * 128 + t]; }
    __syncthreads();

    const float* xb = x + ((long)b << 19);
    int sl = t & 127, chalf = t >> 7;
    #pragma unroll
    for (int c8 = 0; c8 < 8; ++c8) {
        int CH = chalf * 8 + c8;
        u16 tmp[8];
        #pragma unroll
        for (int j = 0; j < 8; ++j) {
            int c = CH * 8 + j;
            float v = xb[((long)c << 12) + s0 + sl];
            tmp[j] = f2bf(v * gpl[c] + bpl[c]);
        }
        *(u16x8*)&ldsT[sl * 128 + ((CH ^ (sl & 15)) << 3)] = *(u16x8*)tmp;
    }
    __syncthreads();

    u16* hnb = hn + ((long)b << 19);
    int s = t >> 1, h = t & 1;
    #pragma unroll
    for (int i = 0; i < 8; ++i) {
        int CH = h * 8 + i;
        u16x8 v = *(u16x8*)&ldsT[s * 128 + ((CH ^ (s & 15)) << 3)];
        *(u16x8*)&hnb[(long)(s0 + s) * 128 + CH * 8] = v;
    }
}

// ============================================================
// Kernel 2: QKV projection via MFMA. Q pre-scaled by SC2 -> bf16
// [b][s][128]; K -> bf16 [b][s][128]; V -> fp16 [b][c][s].
// ============================================================
__global__ __launch_bounds__(256) void qkvm_kernel(
    const u16* __restrict__ hn, const u16* __restrict__ wbf,
    const float* __restrict__ bias,
    u16* __restrict__ Qt, u16* __restrict__ Kt, u16* __restrict__ Vv)
{
    __shared__ u16 ldsH[64 * 128];   // 16 KB
    int tid = threadIdx.x, lane = tid & 63, wv = tid >> 6;
    int g = lane >> 4, t = lane & 15;
    int b = blockIdx.x & 7, stile = blockIdx.x >> 3;
    int s0 = stile << 6;

    const u16* hnb = hn + ((long)b << 19);
    #pragma unroll
    for (int i = 0; i < 4; ++i) {
        int seg = wv * 4 + i;
        int n = seg * 64 + lane;
        int s = n >> 4, SL = n & 15;
        int gch = SL ^ (s & 15);
        gload16(hnb + (long)(s0 + s) * 128 + gch * 8, &ldsH[seg * 512]);
    }
    __syncthreads();

    bf16x8 hf[4];
    int slq = (wv << 4) + t;
    #pragma unroll
    for (int ks = 0; ks < 4; ++ks)
        hf[ks] = *(const bf16x8*)&ldsH[slq * 128 + ((((ks << 2) + g) ^ t) << 3)];

    u16* Qtb = Qt + ((long)b << 19);
    u16* Ktb = Kt + ((long)b << 19);
    u16* Vb  = Vv + ((long)b << 19);
    int srow = s0 + (wv << 4) + (g << 2);

    #pragma unroll
    for (int ot = 0; ot < 8; ++ot) {
        bf16x8 wf[4];
        #pragma unroll
        for (int ks = 0; ks < 4; ++ks)
            wf[ks] = *(const bf16x8*)&wbf[(ot * 16 + t) * 128 + ks * 32 + g * 8];
        float bv = bias[ot * 16 + t];
        f32x4 acc = (f32x4){bv, bv, bv, bv};
        #pragma unroll
        for (int ks = 0; ks < 4; ++ks)
            acc = MFMA32(hf[ks], wf[ks], acc);
        #pragma unroll
        for (int r = 0; r < 4; ++r)
            Qtb[(long)(srow + r) * 128 + ot * 16 + t] = f2bf(acc[r] * SC2);
    }
    #pragma unroll
    for (int ot = 8; ot < 16; ++ot) {
        bf16x8 wf[4];
        #pragma unroll
        for (int ks = 0; ks < 4; ++ks)
            wf[ks] = *(const bf16x8*)&wbf[(ot * 16 + t) * 128 + ks * 32 + g * 8];
        float bv = bias[ot * 16 + t];
        f32x4 acc = (f32x4){bv, bv, bv, bv};
        #pragma unroll
        for (int ks = 0; ks < 4; ++ks)
            acc = MFMA32(hf[ks], wf[ks], acc);
        #pragma unroll
        for (int r = 0; r < 4; ++r)
            Ktb[(long)(srow + r) * 128 + (ot - 8) * 16 + t] = f2bf(acc[r]);
    }
    #pragma unroll
    for (int ot = 16; ot < 24; ++ot) {
        bf16x8 wf[4];
        #pragma unroll
        for (int ks = 0; ks < 4; ++ks)
            wf[ks] = *(const bf16x8*)&wbf[(ot * 16 + t) * 128 + ks * 32 + g * 8];
        float4 b4 = *(const float4*)&bias[ot * 16 + (g << 2)];
        f32x4 acc = (f32x4){b4.x, b4.y, b4.z, b4.w};
        #pragma unroll
        for (int ks = 0; ks < 4; ++ks)
            acc = MFMA32(wf[ks], hf[ks], acc);
        #pragma unroll
        for (int r = 0; r < 4; ++r) {
            int cv = (ot - 16) * 16 + (g << 2) + r;
            Vb[((long)cv << 12) + s0 + (wv << 4) + t] = f2h(acc[r]);
        }
    }
}

// ============================================================
// Kernel 3: MFMA flash attention + final x*a multiply.
// Round-6: QBLK=32 (2 qsets), grid 1024, single-buffered 32KB KV
// tile -> 4 blocks/CU (16 waves/CU). 4-way key split, zero-shuffle
// K=16 fp16 PV. Strength-reduced staging, per-lane partial lsum,
// Q pre-scaled. Per-wave partials merged via LDS at the end.
// ============================================================
__global__ __launch_bounds__(256, 4) void attn_kernel(
    const u16* __restrict__ Qt, const u16* __restrict__ Kt,
    const u16* __restrict__ Vv, const float* __restrict__ x,
    float* __restrict__ out)
{
    __shared__ u16 ldsBuf[16384];        // 32 KB: K [64s][16ch16] | V [128c][16ch8]
    __shared__ float mls[4][2][2][16];   // [wave][qs][{m,l}][t]

    u16* ldsK = ldsBuf;
    u16* ldsV = ldsBuf + 8192;

    int tid = threadIdx.x, lane = tid & 63, wv = tid >> 6;
    int g = lane >> 4, t = lane & 15;
    int b = blockIdx.x & 7, qb = blockIdx.x >> 3;   // XCD-affine batch
    int s0 = qb << 5;                               // 32 q-rows per block

    const u16* Qb = Qt + ((long)b << 19);
    const u16* Kb = Kt + ((long)b << 19);
    const u16* Vb = Vv + ((long)b << 19);

    // Q B-frags (2 qsets), register-resident; already scaled by SC2
    bf16x8 qf[2][4];
    #pragma unroll
    for (int qs = 0; qs < 2; ++qs)
        #pragma unroll
        for (int ks = 0; ks < 4; ++ks)
            qf[qs][ks] = *(const bf16x8*)&Qb[(long)(s0 + qs * 16 + t) * 128 + ks * 32 + g * 8];

    f32x4 acco[2][8];
    #pragma unroll
    for (int qs = 0; qs < 2; ++qs)
        #pragma unroll
        for (int i = 0; i < 8; ++i) acco[qs][i] = (f32x4){0.f, 0.f, 0.f, 0.f};
    float mm[2] = {-3e38f, -3e38f};
    float llp[2] = {0.f, 0.f};   // per-lane partial row-sums

    // strength-reduced staging offsets (u16 element units)
    u32 kofs[4], vofs[4];
    #pragma unroll
    for (int i = 0; i < 4; ++i) {
        int lin = (((wv << 2) + i) << 6) + lane;
        int s = lin >> 4, ch = lin & 15;
        kofs[i] = s * 128 + ((ch ^ (s & 7)) << 3);
        int c = lin >> 3, c8 = lin & 7;
        vofs[i] = c * 4096 + ((c8 ^ ((c >> 1) & 7) ^ ((c & 1) << 2)) << 3);
    }

    // loop-invariant fragment offsets
    int sK = (wv << 4) + t;     // this wave's key row in tile
    u32 kfo[4];
    #pragma unroll
    for (int ks = 0; ks < 4; ++ks)
        kfo[ks] = sK * 128 + ((((ks << 2) + g) ^ (sK & 7)) << 3);
    u32 vfo = (t << 6) + ((((wv << 2) + g) ^ (t & 14) ^ ((t & 1) << 3)) << 2);

    for (int kt = 0; kt < 64; ++kt) {
        // ---- stage 32 KB KV tile (single buffer) ----
        #pragma unroll
        for (int i = 0; i < 4; ++i) {
            gload16(Kb + kofs[i], ldsK + (((wv << 2) + i) << 9));
            gload16(Vb + vofs[i], ldsV + (((wv << 2) + i) << 9));
            kofs[i] += 8192;   // 64 key-rows * 128
            vofs[i] += 64;     // 64 s within V row
        }
        __syncthreads();       // drains vmcnt: tile resident

        // ---- K A-frags (16 keys), reused across both qsets ----
        bf16x8 kf[4];
        #pragma unroll
        for (int ks = 0; ks < 4; ++ks)
            kf[ks] = *(const bf16x8*)&ldsK[kfo[ks]];

        // ---- QK^T: both qsets batched for ILP ----
        f32x4 sa[2];
        __builtin_amdgcn_s_setprio(1);
        #pragma unroll
        for (int qs = 0; qs < 2; ++qs) {
            f32x4 acc = (f32x4){0.f, 0.f, 0.f, 0.f};
            #pragma unroll
            for (int ks = 0; ks < 4; ++ks)
                acc = MFMA32(kf[ks], qf[qs][ks], acc);
            sa[qs] = acc;
        }
        __builtin_amdgcn_s_setprio(0);

        // ---- online softmax (exp2 domain, defer-max, lane-partial l) ----
        f16x4 ppq[2];
        #pragma unroll
        for (int qs = 0; qs < 2; ++qs) {
            float p0 = sa[qs][0], p1 = sa[qs][1], p2 = sa[qs][2], p3 = sa[qs][3];
            float px = fmaxf(fmaxf(p0, p1), fmaxf(p2, p3));
            px = fmaxf(px, __shfl_xor(px, 16));
            px = fmaxf(px, __shfl_xor(px, 32));
            if (!__all(px - mm[qs] <= 12.0f)) {
                float mn = fmaxf(mm[qs], px);
                float al = exp2f(mm[qs] - mn);
                llp[qs] *= al;
                #pragma unroll
                for (int i = 0; i < 8; ++i) {
                    acco[qs][i][0] *= al; acco[qs][i][1] *= al;
                    acco[qs][i][2] *= al; acco[qs][i][3] *= al;
                }
                mm[qs] = mn;
            }
            float e0 = exp2f(p0 - mm[qs]), e1 = exp2f(p1 - mm[qs]);
            float e2 = exp2f(p2 - mm[qs]), e3 = exp2f(p3 - mm[qs]);
            llp[qs] += (e0 + e1) + (e2 + e3);
            f16x4 pp;
            pp[0] = (_Float16)e0; pp[1] = (_Float16)e1;
            pp[2] = (_Float16)e2; pp[3] = (_Float16)e3;
            ppq[qs] = pp;
        }

        // ---- PV: V frag shared by both qsets (16x16x16 f16) ----
        __builtin_amdgcn_s_setprio(1);
        #pragma unroll
        for (int ct = 0; ct < 8; ++ct) {
            f16x4 vf = *(const f16x4*)&ldsV[(ct << 10) + vfo];
            acco[0][ct] = MFMA16(vf, ppq[0], acco[0][ct]);
            acco[1][ct] = MFMA16(vf, ppq[1], acco[1][ct]);
        }
        __builtin_amdgcn_s_setprio(0);

        __syncthreads();       // reads done before next stage overwrites
    }

    // ================= merge epilogue =================
    // reduce lane-partial l across the 4 g-lanes of each row
    float llw0 = llp[0] + __shfl_xor(llp[0], 16);
    llw0 += __shfl_xor(llw0, 32);
    float llw1 = llp[1] + __shfl_xor(llp[1], 16);
    llw1 += __shfl_xor(llw1, 32);
    if (g == 0) {
        mls[wv][0][0][t] = mm[0]; mls[wv][0][1][t] = llw0;
        mls[wv][1][0][t] = mm[1]; mls[wv][1][1][t] = llw1;
    }
    __syncthreads();
    float sc[2];
    #pragma unroll
    for (int qs = 0; qs < 2; ++qs) {
        float m0 = mls[0][qs][0][t], l0 = mls[0][qs][1][t];
        float m1 = mls[1][qs][0][t], l1 = mls[1][qs][1][t];
        float m2 = mls[2][qs][0][t], l2 = mls[2][qs][1][t];
        float m3 = mls[3][qs][0][t], l3 = mls[3][qs][1][t];
        float mf = fmaxf(fmaxf(m0, m1), fmaxf(m2, m3));
        float lf = l0 * exp2f(m0 - mf) + l1 * exp2f(m1 - mf)
                 + l2 * exp2f(m2 - mf) + l3 * exp2f(m3 - mf);
        sc[qs] = exp2f(mm[qs] - mf) / lf;
    }

    // O-merge in 2 channel-halves through the 32 KB buffer, fused x*a
    float* mrg = (float*)ldsBuf;   // [c_local 64][wv 4][q 32]
    const float* xb = x + ((long)b << 19);
    float* ob = out + ((long)b << 19);
    int qq = tid & 31, cq = tid >> 5;

    #pragma unroll
    for (int half = 0; half < 2; ++half) {
        __syncthreads();   // prior reads of mrg/ldsBuf complete
        #pragma unroll
        for (int qs = 0; qs < 2; ++qs)
            #pragma unroll
            for (int ct4 = 0; ct4 < 4; ++ct4) {
                int ct = (half << 2) + ct4;
                #pragma unroll
                for (int r = 0; r < 4; ++r) {
                    int cl = (ct4 << 4) + (g << 2) + r;
                    mrg[(cl << 7) + (wv << 5) + (qs << 4) + t] = acco[qs][ct][r] * sc[qs];
                }
            }
        __syncthreads();
        #pragma unroll
        for (int i = 0; i < 8; ++i) {
            int cl = (i << 3) + cq;
            int base = cl << 7;
            float sum = mrg[base + qq] + mrg[base + 32 + qq]
                      + mrg[base + 64 + qq] + mrg[base + 96 + qq];
            long gi = (((long)((half << 6) + cl)) << 12) + s0 + qq;
            ob[gi] = xb[gi] * sum;
        }
    }
}

// ============================================================
extern "C" void kernel_launch(void* const* d_in, const int* in_sizes, int n_in,
                              void* d_out, int out_size, void* d_ws, size_t ws_size,
                              hipStream_t stream)
{
    const float* x    = (const float*)d_in[0];
    const float* gw   = (const float*)d_in[1];
    const float* gb   = (const float*)d_in[2];
    const float* w    = (const float*)d_in[3];
    const float* bias = (const float*)d_in[4];
    float* out = (float*)d_out;

    u16* hn  = (u16*)d_ws;                        // [8][4096][128] bf16 = 8 MB
    u16* Qt  = hn + (size_t)8 * 4096 * 128;       // [8][4096][128] bf16 = 8 MB
    u16* Kt  = Qt + (size_t)8 * 4096 * 128;       // [8][4096][128] bf16 = 8 MB
    u16* Vv  = Kt + (size_t)8 * 4096 * 128;       // [8][128][4096] fp16 = 8 MB
    u16* wbf = Vv + (size_t)8 * 128 * 4096;       // [384][128] bf16 = 96 KB
    float* gp = (float*)(wbf + (size_t)384 * 128); // [8][128]
    float* bp = gp + 1024;                         // [8][128]

    stats_kernel<<<256, 256, 0, stream>>>(x, gw, gb, gp, bp);
    wconv_kernel<<<48, 256, 0, stream>>>(w, wbf);
    apply_kernel<<<256, 256, 0, stream>>>(x, gp, bp, hn);
    qkvm_kernel<<<512, 256, 0, stream>>>(hn, wbf, bias, Qt, Kt, Vv);
    attn_kernel<<<1024, 256, 0, stream>>>(Qt, Kt, Vv, x, out);
}

// Round 7
// 158.589 us; speedup vs baseline: 1.8596x; 1.8596x over previous
//
#include <hip/hip_runtime.h>
#include <hip/hip_bf16.h>
#include <stdint.h>

typedef unsigned short u16;
typedef unsigned int   u32;
typedef __attribute__((ext_vector_type(8)))  short bf16x8;
typedef __attribute__((ext_vector_type(8)))  unsigned short u16x8;
typedef __attribute__((ext_vector_type(4)))  float f32x4;
typedef __attribute__((ext_vector_type(16))) float f32x16;

// SCALE * log2(e): applied to raw scores, exp2 domain
#define SC2 0.1275174475f

#define MFMA3216(A, B, C) __builtin_amdgcn_mfma_f32_32x32x16_bf16(A, B, C, 0, 0, 0)
#define MFMA1632(A, B, C) __builtin_amdgcn_mfma_f32_16x16x32_bf16(A, B, C, 0, 0, 0)

__device__ __forceinline__ float bf2f(u16 u) {
    union { u32 i; float f; } t; t.i = ((u32)u) << 16; return t.f;
}
__device__ __forceinline__ u16 f2bf(float f) {
    union { u32 i; float f; } t; t.f = f;
    u32 b = t.i;
    return (u16)((b + 0x7fffu + ((b >> 16) & 1u)) >> 16);
}
// pack two floats to bf16 pair (low = first arg)
__device__ __forceinline__ u32 packbf(float a, float b) {
    union { __hip_bfloat162 h; u32 u; } c;
    c.h = __float22bfloat162_rn(float2{a, b});
    return c.u;
}

// async global->LDS, 16B per lane, linear LDS dest (wave-uniform base + lane*16)
__device__ __forceinline__ void gload16(const u16* g, u16* l) {
    __builtin_amdgcn_global_load_lds(
        (const __attribute__((address_space(1))) void*)g,
        (__attribute__((address_space(3))) void*)l, 16, 0, 0);
}

// ============================================================
// Kernel 0: GroupNorm stats -> per-channel affine tables.
// ============================================================
__global__ __launch_bounds__(256) void stats_kernel(
    const float* __restrict__ x, const float* __restrict__ gw,
    const float* __restrict__ gb, float* __restrict__ gp, float* __restrict__ bp)
{
    int b = blockIdx.x & 7, g = blockIdx.x >> 3;
    long base = ((long)(b * 128 + g * 4)) << 12;
    const float4* x4 = (const float4*)(x + base);

    float s = 0.f, ss = 0.f;
    for (int i = threadIdx.x; i < 4096; i += 256) {
        float4 v = x4[i];
        s  += v.x + v.y + v.z + v.w;
        ss += v.x * v.x + v.y * v.y + v.z * v.z + v.w * v.w;
    }
    #pragma unroll
    for (int off = 32; off > 0; off >>= 1) {
        s  += __shfl_xor(s,  off);
        ss += __shfl_xor(ss, off);
    }
    __shared__ float red[8];
    int wid = threadIdx.x >> 6;
    if ((threadIdx.x & 63) == 0) { red[wid * 2] = s; red[wid * 2 + 1] = ss; }
    __syncthreads();
    s  = red[0] + red[2] + red[4] + red[6];
    ss = red[1] + red[3] + red[5] + red[7];

    float mean = s * (1.f / 16384.f);
    float var  = ss * (1.f / 16384.f) - mean * mean;
    float rs   = rsqrtf(var + 1e-5f);

    if (threadIdx.x < 4) {
        int c = g * 4 + threadIdx.x;
        float gamma = gw[c] * rs;
        gp[b * 128 + c] = gamma;
        bp[b * 128 + c] = gb[c] - mean * gamma;
    }
}

// ============================================================
// Kernel 0b: w fp32 -> bf16
// ============================================================
__global__ __launch_bounds__(256) void wconv_kernel(
    const float* __restrict__ w, u16* __restrict__ wbf)
{
    int idx = (blockIdx.x * 256 + threadIdx.x) * 4;
    float4 v = *(const float4*)&w[idx];
    ushort4 o = { f2bf(v.x), f2bf(v.y), f2bf(v.z), f2bf(v.w) };
    *(ushort4*)&wbf[idx] = o;
}

// ============================================================
// Kernel 1: apply GN + transpose -> hn [b][s][c] bf16.
// ============================================================
__global__ __launch_bounds__(256) void apply_kernel(
    const float* __restrict__ x, const float* __restrict__ gp,
    const float* __restrict__ bp, u16* __restrict__ hn)
{
    __shared__ u16 ldsT[128 * 128];   // 32 KB
    __shared__ float gpl[128], bpl[128];
    int b = blockIdx.x & 7, st = blockIdx.x >> 3;
    int s0 = st << 7;
    int t = threadIdx.x;
    if (t < 128) { gpl[t] = gp[b * 128 + t]; bpl[t] = bp[b * 128 + t]; }
    __syncthreads();

    const float* xb = x + ((long)b << 19);
    int sl = t & 127, chalf = t >> 7;
    #pragma unroll
    for (int c8 = 0; c8 < 8; ++c8) {
        int CH = chalf * 8 + c8;
        u16 tmp[8];
        #pragma unroll
        for (int j = 0; j < 8; ++j) {
            int c = CH * 8 + j;
            float v = xb[((long)c << 12) + s0 + sl];
            tmp[j] = f2bf(v * gpl[c] + bpl[c]);
        }
        *(u16x8*)&ldsT[sl * 128 + ((CH ^ (sl & 15)) << 3)] = *(u16x8*)tmp;
    }
    __syncthreads();

    u16* hnb = hn + ((long)b << 19);
    int s = t >> 1, h = t & 1;
    #pragma unroll
    for (int i = 0; i < 8; ++i) {
        int CH = h * 8 + i;
        u16x8 v = *(u16x8*)&ldsT[s * 128 + ((CH ^ (s & 15)) << 3)];
        *(u16x8*)&hnb[(long)(s0 + s) * 128 + CH * 8] = v;
    }
}

// ============================================================
// Kernel 2: QKV projection via MFMA (16x16x32, proven). Q,K -> bf16
// [b][s][128] (NOT pre-scaled); V -> bf16 [b][c][s].
// ============================================================
__global__ __launch_bounds__(256) void qkvm_kernel(
    const u16* __restrict__ hn, const u16* __restrict__ wbf,
    const float* __restrict__ bias,
    u16* __restrict__ Qt, u16* __restrict__ Kt, u16* __restrict__ Vv)
{
    __shared__ u16 ldsH[64 * 128];   // 16 KB
    int tid = threadIdx.x, lane = tid & 63, wv = tid >> 6;
    int g = lane >> 4, t = lane & 15;
    int b = blockIdx.x & 7, stile = blockIdx.x >> 3;
    int s0 = stile << 6;

    const u16* hnb = hn + ((long)b << 19);
    #pragma unroll
    for (int i = 0; i < 4; ++i) {
        int seg = wv * 4 + i;
        int n = seg * 64 + lane;
        int s = n >> 4, SL = n & 15;
        int gch = SL ^ (s & 15);
        gload16(hnb + (long)(s0 + s) * 128 + gch * 8, &ldsH[seg * 512]);
    }
    __syncthreads();

    bf16x8 hf[4];
    int slq = (wv << 4) + t;
    #pragma unroll
    for (int ks = 0; ks < 4; ++ks)
        hf[ks] = *(const bf16x8*)&ldsH[slq * 128 + ((((ks << 2) + g) ^ t) << 3)];

    u16* Qtb = Qt + ((long)b << 19);
    u16* Ktb = Kt + ((long)b << 19);
    u16* Vb  = Vv + ((long)b << 19);
    int srow = s0 + (wv << 4) + (g << 2);

    #pragma unroll
    for (int ot = 0; ot < 8; ++ot) {
        bf16x8 wf[4];
        #pragma unroll
        for (int ks = 0; ks < 4; ++ks)
            wf[ks] = *(const bf16x8*)&wbf[(ot * 16 + t) * 128 + ks * 32 + g * 8];
        float bv = bias[ot * 16 + t];
        f32x4 acc = (f32x4){bv, bv, bv, bv};
        #pragma unroll
        for (int ks = 0; ks < 4; ++ks)
            acc = MFMA1632(hf[ks], wf[ks], acc);
        #pragma unroll
        for (int r = 0; r < 4; ++r)
            Qtb[(long)(srow + r) * 128 + ot * 16 + t] = f2bf(acc[r]);
    }
    #pragma unroll
    for (int ot = 8; ot < 16; ++ot) {
        bf16x8 wf[4];
        #pragma unroll
        for (int ks = 0; ks < 4; ++ks)
            wf[ks] = *(const bf16x8*)&wbf[(ot * 16 + t) * 128 + ks * 32 + g * 8];
        float bv = bias[ot * 16 + t];
        f32x4 acc = (f32x4){bv, bv, bv, bv};
        #pragma unroll
        for (int ks = 0; ks < 4; ++ks)
            acc = MFMA1632(hf[ks], wf[ks], acc);
        #pragma unroll
        for (int r = 0; r < 4; ++r)
            Ktb[(long)(srow + r) * 128 + (ot - 8) * 16 + t] = f2bf(acc[r]);
    }
    #pragma unroll
    for (int ot = 16; ot < 24; ++ot) {
        bf16x8 wf[4];
        #pragma unroll
        for (int ks = 0; ks < 4; ++ks)
            wf[ks] = *(const bf16x8*)&wbf[(ot * 16 + t) * 128 + ks * 32 + g * 8];
        float4 b4 = *(const float4*)&bias[ot * 16 + (g << 2)];
        f32x4 acc = (f32x4){b4.x, b4.y, b4.z, b4.w};
        #pragma unroll
        for (int ks = 0; ks < 4; ++ks)
            acc = MFMA1632(wf[ks], hf[ks], acc);
        #pragma unroll
        for (int r = 0; r < 4; ++r) {
            int cv = (ot - 16) * 16 + (g << 2) + r;
            Vb[((long)cv << 12) + s0 + (wv << 4) + t] = f2bf(acc[r]);
        }
    }
}

// ============================================================
// Kernel 3: flash attention via 32x32x16 MFMA + final x*a.
// 4 waves = 2 q-splits (wq: 32 rows each) x 2 key-splits (wk: 32
// keys of each 64-key tile). Per wave-tile: QK = 8 MFMA (K-frags
// b128 from swizzled LDS, Q register-resident), softmax per-lane
// scalar (D col = q-row), P->bf16 pairs via cvt_pk + 4 shfl_xor(32),
// PV = 8 MFMA (V-frags b128). Double-buffered KV staging. wk-halves
// merged through dual 32KB LDS buffers in the epilogue.
// ============================================================
__global__ __launch_bounds__(256) void attn_kernel(
    const u16* __restrict__ Qt, const u16* __restrict__ Kt,
    const u16* __restrict__ Vv, const float* __restrict__ x,
    float* __restrict__ out)
{
    __shared__ u16 ldsK[2][8192];      // [64 key][16 ch16], src chunk ^= key&7
    __shared__ u16 ldsV[2][8192];      // [128 c][8 ch16],  src chunk ^= c&7
    __shared__ float mls[2][2][2][32]; // [wq][wk][{m,l}][q5]

    int tid = threadIdx.x, lane = tid & 63, wv = tid >> 6;
    int wq = wv >> 1, wk = wv & 1;
    int q5 = lane & 31, h = lane >> 5;
    int b = blockIdx.x & 7, qb = blockIdx.x >> 3;
    int s0 = qb << 6;

    const u16* Qb = Qt + ((long)b << 19);
    const u16* Kb = Kt + ((long)b << 19);
    const u16* Vb = Vv + ((long)b << 19);

    // Q B-frags: col q = lane&31, k-run = d0 + 8h .. +7, d0 = 16*d
    bf16x8 qf[8];
    {
        long qrow = (long)(s0 + (wq << 5) + q5) << 7;
        #pragma unroll
        for (int d = 0; d < 8; ++d)
            qf[d] = *(const bf16x8*)&Qb[qrow + (d << 4) + (h << 3)];
    }

    f32x16 acco[4];
    #pragma unroll
    for (int cb = 0; cb < 4; ++cb)
        #pragma unroll
        for (int r = 0; r < 16; ++r) acco[cb][r] = 0.f;
    float m = -3e38f, llp = 0.f;

    // staging offsets (u16 units), strength-reduced
    u32 kso[4], vso[4];
    #pragma unroll
    for (int i = 0; i < 4; ++i) {
        int idx = (((wv << 2) + i) << 6) + lane;
        int s = idx >> 4, ch = idx & 15;
        kso[i] = s * 128 + ((ch ^ (s & 7)) << 3);
        int c = idx >> 3, c8 = idx & 7;
        vso[i] = c * 4096 + ((c8 ^ (c & 7)) << 3);
    }

    // fragment read offsets (loop-invariant)
    int sKey = (wk << 5) + q5;         // this wave's key row in tile
    u32 kfo[8];
    #pragma unroll
    for (int d = 0; d < 8; ++d) {
        int ch = (d << 1) + h;
        kfo[d] = sKey * 128 + ((ch ^ (sKey & 7)) << 3);
    }
    u32 vfo[8];
    #pragma unroll
    for (int cb = 0; cb < 4; ++cb)
        #pragma unroll
        for (int ks = 0; ks < 2; ++ks) {
            int c = (cb << 5) + q5;
            int ch8 = (wk << 2) + (ks << 1) + h;
            vfo[cb * 2 + ks] = c * 64 + ((ch8 ^ (c & 7)) << 3);
        }

    auto STAGE = [&](int buf) {
        #pragma unroll
        for (int i = 0; i < 4; ++i) {
            int seg = (wv << 2) + i;
            gload16(Kb + kso[i], &ldsK[buf][seg << 9]);
            gload16(Vb + vso[i], &ldsV[buf][seg << 9]);
            kso[i] += 8192;   // next 64 key-rows
            vso[i] += 64;     // next 64 s within V row
        }
    };

    STAGE(0);
    __syncthreads();
    int cur = 0;

    for (int kt = 0; kt < 64; ++kt) {
        if (kt < 63) STAGE(cur ^ 1);

        const u16* lK = ldsK[cur];
        const u16* lV = ldsV[cur];

        // ---- QK^T: S^T[key][q] (32x32), 8 d-slices ----
        bf16x8 kf[8];
        #pragma unroll
        for (int d = 0; d < 8; ++d)
            kf[d] = *(const bf16x8*)&lK[kfo[d]];

        f32x16 s;
        #pragma unroll
        for (int r = 0; r < 16; ++r) s[r] = 0.f;
        __builtin_amdgcn_s_setprio(1);
        #pragma unroll
        for (int d = 0; d < 8; ++d)
            s = MFMA3216(kf[d], qf[d], s);
        __builtin_amdgcn_s_setprio(0);

        // ---- softmax: lane owns q-row q5; key(r) = (r&3)+8(r>>2)+4h ----
        float px = s[0];
        #pragma unroll
        for (int r = 1; r < 16; ++r) px = fmaxf(px, s[r]);
        px = fmaxf(px, __shfl_xor(px, 32));
        px *= SC2;
        if (!__all(px - m <= 12.0f)) {
            float mn = fmaxf(m, px);
            float al = exp2f(m - mn);
            llp *= al;
            #pragma unroll
            for (int cb = 0; cb < 4; ++cb)
                #pragma unroll
                for (int r = 0; r < 16; ++r) acco[cb][r] *= al;
            m = mn;
        }
        float e[16];
        float psum = 0.f;
        #pragma unroll
        for (int r = 0; r < 16; ++r) {
            e[r] = exp2f(fmaf(s[r], SC2, -m));
            psum += e[r];
        }
        llp += psum;

        // ---- P -> bf16 pairs; build PV B-frags (keys 16ks+8h+2r,+1) ----
        // pk[i][j]: keys (8i+4h+2j, +1) -> pair-id 4i+2h+j
        u32 pk0[2], pk1[2], pk2[2], pk3[2];
        pk0[0] = packbf(e[0],  e[1]);  pk0[1] = packbf(e[2],  e[3]);
        pk1[0] = packbf(e[4],  e[5]);  pk1[1] = packbf(e[6],  e[7]);
        pk2[0] = packbf(e[8],  e[9]);  pk2[1] = packbf(e[10], e[11]);
        pk3[0] = packbf(e[12], e[13]); pk3[1] = packbf(e[14], e[15]);
        u32 t0[2], t1[2];
        #pragma unroll
        for (int j = 0; j < 2; ++j) {
            t0[j] = (u32)__shfl_xor((int)(h ? pk0[j] : pk1[j]), 32);
            t1[j] = (u32)__shfl_xor((int)(h ? pk2[j] : pk3[j]), 32);
        }
        union { u32 u[4]; bf16x8 v; } pb0, pb1;
        pb0.u[0] = h ? t0[0]  : pk0[0];
        pb0.u[1] = h ? t0[1]  : pk0[1];
        pb0.u[2] = h ? pk1[0] : t0[0];
        pb0.u[3] = h ? pk1[1] : t0[1];
        pb1.u[0] = h ? t1[0]  : pk2[0];
        pb1.u[1] = h ? t1[1]  : pk2[1];
        pb1.u[2] = h ? pk3[0] : t1[0];
        pb1.u[3] = h ? pk3[1] : t1[1];

        // ---- PV: O^T[c][q] += V[c][k] * P^T[k][q], 4 c-blocks x 2 ks ----
        __builtin_amdgcn_s_setprio(1);
        #pragma unroll
        for (int cb = 0; cb < 4; ++cb) {
            bf16x8 v0 = *(const bf16x8*)&lV[vfo[cb * 2 + 0]];
            acco[cb] = MFMA3216(v0, pb0.v, acco[cb]);
            bf16x8 v1 = *(const bf16x8*)&lV[vfo[cb * 2 + 1]];
            acco[cb] = MFMA3216(v1, pb1.v, acco[cb]);
        }
        __builtin_amdgcn_s_setprio(0);

        __syncthreads();
        cur ^= 1;
    }

    // ================= merge epilogue =================
    float ll = llp + __shfl_xor(llp, 32);
    if (h == 0) { mls[wq][wk][0][q5] = m; mls[wq][wk][1][q5] = ll; }
    __syncthreads();
    float mo = mls[wq][wk ^ 1][0][q5], lo = mls[wq][wk ^ 1][1][q5];
    float mf = fmaxf(m, mo);
    float lf = ll * exp2f(m - mf) + lo * exp2f(mo - mf);
    float sc = exp2f(m - mf) / lf;

    // each wk-half writes its scaled partial into its own 32KB buffer
    float* mrg = (wk == 0) ? (float*)&ldsK[0][0] : (float*)&ldsV[0][0];
    #pragma unroll
    for (int cb = 0; cb < 4; ++cb)
        #pragma unroll
        for (int r = 0; r < 16; ++r) {
            int c = (cb << 5) + (r & 3) + ((r >> 2) << 3) + (h << 2);
            mrg[(c << 6) + (wq << 5) + q5] = acco[cb][r] * sc;
        }
    __syncthreads();

    // final: out = x * (O_wk0 + O_wk1), coalesced
    const float* mA = (const float*)&ldsK[0][0];
    const float* mB = (const float*)&ldsV[0][0];
    const float* xb = x + ((long)b << 19);
    float* ob = out + ((long)b << 19);
    int q6 = tid & 63, c0 = tid >> 6;
    #pragma unroll 8
    for (int i = 0; i < 32; ++i) {
        int c = (i << 2) + c0;
        float v = mA[(c << 6) + q6] + mB[(c << 6) + q6];
        long gi = ((long)c << 12) + s0 + q6;
        ob[gi] = xb[gi] * v;
    }
}

// ============================================================
extern "C" void kernel_launch(void* const* d_in, const int* in_sizes, int n_in,
                              void* d_out, int out_size, void* d_ws, size_t ws_size,
                              hipStream_t stream)
{
    const float* x    = (const float*)d_in[0];
    const float* gw   = (const float*)d_in[1];
    const float* gb   = (const float*)d_in[2];
    const float* w    = (const float*)d_in[3];
    const float* bias = (const float*)d_in[4];
    float* out = (float*)d_out;

    u16* hn  = (u16*)d_ws;                        // [8][4096][128] bf16 = 8 MB
    u16* Qt  = hn + (size_t)8 * 4096 * 128;       // [8][4096][128] bf16 = 8 MB
    u16* Kt  = Qt + (size_t)8 * 4096 * 128;       // [8][4096][128] bf16 = 8 MB
    u16* Vv  = Kt + (size_t)8 * 4096 * 128;       // [8][128][4096] bf16 = 8 MB
    u16* wbf = Vv + (size_t)8 * 128 * 4096;       // [384][128] bf16 = 96 KB
    float* gp = (float*)(wbf + (size_t)384 * 128); // [8][128]
    float* bp = gp + 1024;                         // [8][128]

    stats_kernel<<<256, 256, 0, stream>>>(x, gw, gb, gp, bp);
    wconv_kernel<<<48, 256, 0, stream>>>(w, wbf);
    apply_kernel<<<256, 256, 0, stream>>>(x, gp, bp, hn);
    qkvm_kernel<<<512, 256, 0, stream>>>(hn, wbf, bias, Qt, Kt, Vv);
    attn_kernel<<<512, 256, 0, stream>>>(Qt, Kt, Vv, x, out);
}